// Round 4
// baseline (413.260 us; speedup 1.0000x reference)
//
#include <hip/hip_runtime.h>
#include <hip/hip_bf16.h>

#define N_NODES 100000
#define N0_ROWS 60000
#define N1_ROWS 40000
#define NE 1600000
#define HD 128
#define NB 782           // ceil(100000/128) buckets of 128 nodes
#define BSH 128          // nodes per bucket
#define EPB 2560         // edges per partition block
#define NBLK 625         // NE / EPB exactly

typedef __attribute__((ext_vector_type(8))) short short8;
typedef __attribute__((ext_vector_type(4))) float f32x4;

__device__ __forceinline__ float bf16lo(unsigned v) { return __uint_as_float(v << 16); }
__device__ __forceinline__ float bf16hi(unsigned v) { return __uint_as_float(v & 0xFFFF0000u); }

__device__ __forceinline__ unsigned short f2bf_rne(float f) {
    unsigned u = __float_as_uint(f);
    return (unsigned short)((u + 0x7FFFu + ((u >> 16) & 1u)) >> 16);
}
__device__ __forceinline__ unsigned pack2_rne(float lo, float hi) {
    unsigned a = __float_as_uint(lo); a = (a + 0x7FFFu + ((a >> 16) & 1u)) >> 16;
    unsigned b = __float_as_uint(hi); b = (b + 0x7FFFu + ((b >> 16) & 1u)) & 0xFFFF0000u;
    return (a & 0xFFFFu) | b;
}
__device__ __forceinline__ float sigmoidf_(float v) { return 1.0f / (1.0f + __expf(-v)); }

// ============ CSR build: radix-partition (no global atomics) ============
__global__ __launch_bounds__(256) void k_phist(const int* __restrict__ dst,
                                               int* __restrict__ cnt) {
    __shared__ int h[NB];
    int blk = blockIdx.x;
    for (int i = threadIdx.x; i < NB; i += 256) h[i] = 0;
    __syncthreads();
    int e0 = blk * EPB;
    for (int e = e0 + threadIdx.x; e < e0 + EPB; e += 256)
        atomicAdd(&h[dst[e] >> 7], 1);
    __syncthreads();
    for (int i = threadIdx.x; i < NB; i += 256)
        cnt[i * NBLK + blk] = h[i];
}

__global__ __launch_bounds__(64) void k_colscan(int* __restrict__ cnt,
                                                int* __restrict__ bcnt) {
    int b = blockIdx.x, lane = threadIdx.x & 63;
    int* col = cnt + (size_t)b * NBLK;
    int carry = 0;
    for (int base = 0; base < NBLK; base += 64) {
        int i = base + lane;
        int v = (i < NBLK) ? col[i] : 0;
        int s = v;
        #pragma unroll
        for (int off = 1; off < 64; off <<= 1) {
            int t = __shfl_up(s, off);
            if (lane >= off) s += t;
        }
        if (i < NBLK) col[i] = carry + s - v;
        carry += __shfl(s, 63);
    }
    if (lane == 0) bcnt[b] = carry;
}

__global__ void k_bscan(const int* __restrict__ bcnt, int* __restrict__ boff,
                        int* __restrict__ rowptr) {
    int lane = threadIdx.x & 63;
    const int CH = (NB + 63) / 64;   // 13
    int base = lane * CH;
    int t = 0;
    for (int c = 0; c < CH; ++c) {
        int i = base + c;
        t += (i < NB) ? bcnt[i] : 0;
    }
    int s = t;
    #pragma unroll
    for (int off = 1; off < 64; off <<= 1) {
        int u = __shfl_up(s, off);
        if (lane >= off) s += u;
    }
    int running = s - t;
    for (int c = 0; c < CH; ++c) {
        int i = base + c;
        if (i < NB) {
            boff[i] = running;
            running += bcnt[i];
        }
    }
    if (lane == 0) { boff[NB] = NE; rowptr[N_NODES] = NE; }
}

__global__ __launch_bounds__(256) void k_pplace(const int* __restrict__ src,
                                                const int* __restrict__ dst,
                                                const int* __restrict__ boff,
                                                const int* __restrict__ cnt,
                                                unsigned* __restrict__ ebuf) {
    __shared__ int h[NB];
    int blk = blockIdx.x;
    for (int i = threadIdx.x; i < NB; i += 256) h[i] = cnt[i * NBLK + blk];
    __syncthreads();
    int e0 = blk * EPB;
    for (int e = e0 + threadIdx.x; e < e0 + EPB; e += 256) {
        int d = dst[e];
        int b = d >> 7;
        int pos = atomicAdd(&h[b], 1);
        ebuf[boff[b] + pos] = ((unsigned)(d & 127) << 17) | (unsigned)src[e];
    }
}

__global__ __launch_bounds__(256) void k_bplace(const unsigned* __restrict__ ebuf,
                                                const int* __restrict__ boff,
                                                int* __restrict__ rowptr,
                                                float* __restrict__ invd,
                                                int* __restrict__ eidx) {
    __shared__ int cnt[BSH], off[BSH], lcnt[BSH];
    int b = blockIdx.x, tid = threadIdx.x;
    int e0 = boff[b], e1 = boff[b + 1];
    for (int i = tid; i < BSH; i += 256) { cnt[i] = 0; lcnt[i] = 0; }
    __syncthreads();
    for (int e = e0 + tid; e < e1; e += 256)
        atomicAdd(&cnt[ebuf[e] >> 17], 1);
    __syncthreads();
    if (tid < 64) {
        int lane = tid;
        int c0 = cnt[2 * lane], c1 = cnt[2 * lane + 1];
        int t = c0 + c1, s = t;
        #pragma unroll
        for (int o = 1; o < 64; o <<= 1) {
            int u = __shfl_up(s, o);
            if (lane >= o) s += u;
        }
        int excl = s - t;
        off[2 * lane] = excl;
        off[2 * lane + 1] = excl + c0;
    }
    __syncthreads();
    for (int i = tid; i < BSH; i += 256) {
        int node = b * BSH + i;
        if (node < N_NODES) {
            rowptr[node] = e0 + off[i];
            invd[node] = 1.0f / fmaxf((float)cnt[i], 1.0f);
        }
    }
    for (int e = e0 + tid; e < e1; e += 256) {
        unsigned ent = ebuf[e];
        int d = ent >> 17;
        int pos = e0 + off[d] + atomicAdd(&lcnt[d], 1);
        eidx[pos] = (int)(ent & 0x1FFFFu);
    }
}

// ============ weight prep: all 5 weights, one launch ============
__global__ void prep_w_all(const float* __restrict__ W0, unsigned short* __restrict__ T0,   // 512x128
                           const float* __restrict__ W1, unsigned short* __restrict__ T1,   // 256x128
                           const float* __restrict__ W2, unsigned short* __restrict__ T2,   // 128x128
                           const float* __restrict__ W3, unsigned short* __restrict__ T3,   // 128x128
                           const float* __restrict__ W4, unsigned short* __restrict__ T4) { // 128x16
    int gid = blockIdx.x * blockDim.x + threadIdx.x;
    int stride = gridDim.x * blockDim.x;
    const int S0 = 512 * 128, S1 = 256 * 128, S2 = 128 * 128, S3 = 128 * 128, S4 = 128 * 16;
    const int E1 = S0 + S1, E2 = E1 + S2, E3 = E2 + S3, E4 = E3 + S4;
    for (int i = gid; i < E4; i += stride) {
        if (i < S0) {
            int n = i / 512, k = i - n * 512;
            T0[i] = f2bf_rne(W0[k * 128 + n]);
        } else if (i < E1) {
            int j = i - S0; int n = j / 256, k = j - n * 256;
            T1[j] = f2bf_rne(W1[k * 128 + n]);
        } else if (i < E2) {
            int j = i - E1; int n = j / 128, k = j - n * 128;
            T2[j] = f2bf_rne(W2[k * 128 + n]);
        } else if (i < E3) {
            int j = i - E2; int n = j / 128, k = j - n * 128;
            T3[j] = f2bf_rne(W3[k * 128 + n]);
        } else {
            int j = i - E3; int n = j / 128, k = j - n * 128;
            T4[j] = f2bf_rne(W4[k * 16 + n]);
        }
    }
}

// ============ input projection: feat(f32) @ W + b -> h(bf16) ============
template <int K>
__global__ __launch_bounds__(256, 2) void k_proj(const float* __restrict__ feat,
                                                 const unsigned short* __restrict__ Wt,
                                                 const float* __restrict__ bias,
                                                 unsigned short* __restrict__ hout,
                                                 int rows, int row_off) {
    const int lane = threadIdx.x & 63, wid = threadIdx.x >> 6;
    const int g = lane >> 4, r16 = lane & 15;
    const int colbase = wid * 32;
    constexpr int KC = K / 32;

    short8 fb[2][KC];
    #pragma unroll
    for (int nt = 0; nt < 2; ++nt) {
        int n = colbase + nt * 16 + r16;
        #pragma unroll
        for (int kc = 0; kc < KC; ++kc)
            fb[nt][kc] = *reinterpret_cast<const short8*>(Wt + (size_t)n * K + kc * 32 + g * 8);
    }
    float bv[2];
    bv[0] = bias[colbase + r16];
    bv[1] = bias[colbase + 16 + r16];

    const int ntiles = rows / 16;
    for (int tile = blockIdx.x; tile < ntiles; tile += gridDim.x) {
        const float* ap = feat + (size_t)(tile * 16 + r16) * K;
        f32x4 acc0 = {0.f, 0.f, 0.f, 0.f};
        f32x4 acc1 = {0.f, 0.f, 0.f, 0.f};
        #pragma unroll
        for (int kc = 0; kc < KC; ++kc) {
            const float4* p = reinterpret_cast<const float4*>(ap + kc * 32 + g * 8);
            float4 x0 = p[0], x1 = p[1];
            union { unsigned u[4]; short8 v; } cvt;
            cvt.u[0] = __builtin_amdgcn_perm(__float_as_uint(x0.y), __float_as_uint(x0.x), 0x07060302u);
            cvt.u[1] = __builtin_amdgcn_perm(__float_as_uint(x0.w), __float_as_uint(x0.z), 0x07060302u);
            cvt.u[2] = __builtin_amdgcn_perm(__float_as_uint(x1.y), __float_as_uint(x1.x), 0x07060302u);
            cvt.u[3] = __builtin_amdgcn_perm(__float_as_uint(x1.w), __float_as_uint(x1.z), 0x07060302u);
            acc0 = __builtin_amdgcn_mfma_f32_16x16x32_bf16(cvt.v, fb[0][kc], acc0, 0, 0, 0);
            acc1 = __builtin_amdgcn_mfma_f32_16x16x32_bf16(cvt.v, fb[1][kc], acc1, 0, 0, 0);
        }
        #pragma unroll
        for (int r = 0; r < 4; ++r) {
            size_t orow = (size_t)(row_off + tile * 16 + g * 4 + r);
            hout[orow * HD + colbase + r16]      = f2bf_rne(acc0[r] + bv[0]);
            hout[orow * HD + colbase + 16 + r16] = f2bf_rne(acc1[r] + bv[1]);
        }
    }
}

// ============ pure GEMM: z = h @ W (128->128), bf16 out, no bias ============
__global__ __launch_bounds__(256, 4) void k_z_gemm(const unsigned short* __restrict__ x,
                                                   const unsigned short* __restrict__ Wt,
                                                   unsigned short* __restrict__ zout) {
    const int lane = threadIdx.x & 63, wid = threadIdx.x >> 6;
    const int g = lane >> 4, r16 = lane & 15;
    const int colbase = wid * 32;

    short8 fb[2][4];
    #pragma unroll
    for (int nt = 0; nt < 2; ++nt) {
        int n = colbase + nt * 16 + r16;
        #pragma unroll
        for (int kc = 0; kc < 4; ++kc)
            fb[nt][kc] = *reinterpret_cast<const short8*>(Wt + (size_t)n * HD + kc * 32 + g * 8);
    }

    const int ntiles = N_NODES / 16;  // 6250
    for (int tile = blockIdx.x; tile < ntiles; tile += gridDim.x) {
        const unsigned short* ap = x + (size_t)(tile * 16 + r16) * HD;
        f32x4 acc0 = {0.f, 0.f, 0.f, 0.f};
        f32x4 acc1 = {0.f, 0.f, 0.f, 0.f};
        #pragma unroll
        for (int kc = 0; kc < 4; ++kc) {
            short8 fa = *reinterpret_cast<const short8*>(ap + kc * 32 + g * 8);
            acc0 = __builtin_amdgcn_mfma_f32_16x16x32_bf16(fa, fb[0][kc], acc0, 0, 0, 0);
            acc1 = __builtin_amdgcn_mfma_f32_16x16x32_bf16(fa, fb[1][kc], acc1, 0, 0, 0);
        }
        #pragma unroll
        for (int r = 0; r < 4; ++r) {
            size_t orow = (size_t)(tile * 16 + g * 4 + r);
            zout[orow * HD + colbase + r16]      = f2bf_rne(acc0[r]);
            zout[orow * HD + colbase + 16 + r16] = f2bf_rne(acc1[r]);
        }
    }
}

// ============ aggregate z (128-wide) + bias + sigmoid -> h(bf16) ============
__global__ __launch_bounds__(256, 4) void k_aggz(const unsigned short* __restrict__ z,
                                                 const int* __restrict__ rowptr,
                                                 const int* __restrict__ eidx,
                                                 const float* __restrict__ invd,
                                                 const float* __restrict__ bias,
                                                 unsigned short* __restrict__ hout) {
    const unsigned* zp = reinterpret_cast<const unsigned*>(z);
    unsigned* hp = reinterpret_cast<unsigned*>(hout);
    int lane = threadIdx.x & 63, wid = threadIdx.x >> 6;
    float blo = bias[2 * lane], bhi = bias[2 * lane + 1];
    int nwaves = gridDim.x * 4;
    for (int node = blockIdx.x * 4 + wid; node < N_NODES; node += nwaves) {
        int rp0 = rowptr[node], rp1 = rowptr[node + 1];
        float a0 = 0.f, a1 = 0.f;
        for (int base = rp0; base < rp1; base += 64) {
            int m = rp1 - base; if (m > 64) m = 64;
            int idx = (lane < m) ? eidx[base + lane] : 0;
            int t = 0;
            for (; t + 4 <= m; t += 4) {
                int j0 = __shfl(idx, t), j1 = __shfl(idx, t + 1);
                int j2 = __shfl(idx, t + 2), j3 = __shfl(idx, t + 3);
                unsigned v0 = zp[(size_t)j0 * 64 + lane];
                unsigned v1 = zp[(size_t)j1 * 64 + lane];
                unsigned v2 = zp[(size_t)j2 * 64 + lane];
                unsigned v3 = zp[(size_t)j3 * 64 + lane];
                a0 += bf16lo(v0) + bf16lo(v1) + bf16lo(v2) + bf16lo(v3);
                a1 += bf16hi(v0) + bf16hi(v1) + bf16hi(v2) + bf16hi(v3);
            }
            for (; t < m; ++t) {
                int j = __shfl(idx, t);
                unsigned v = zp[(size_t)j * 64 + lane];
                a0 += bf16lo(v); a1 += bf16hi(v);
            }
        }
        unsigned zv = zp[(size_t)node * 64 + lane];
        float s = invd[node];
        hp[(size_t)node * 64 + lane] = pack2_rne(sigmoidf_(bf16lo(zv) + s * a0 + blo),
                                                 sigmoidf_(bf16hi(zv) + s * a1 + bhi));
    }
}

// ============ z3 = x @ Wout (128->16), bf16 out, no bias ============
__global__ __launch_bounds__(256, 4) void k_zout_gemm(const unsigned short* __restrict__ x,
                                                      const unsigned short* __restrict__ Wt,
                                                      unsigned short* __restrict__ z3) {
    const int lane = threadIdx.x & 63, wid = threadIdx.x >> 6;
    const int g = lane >> 4, r16 = lane & 15;

    short8 fb[4];
    #pragma unroll
    for (int kc = 0; kc < 4; ++kc)
        fb[kc] = *reinterpret_cast<const short8*>(Wt + (size_t)r16 * HD + kc * 32 + g * 8);

    const int ntiles = N_NODES / 16;  // 6250
    for (int tile = blockIdx.x * 4 + wid; tile < ntiles; tile += gridDim.x * 4) {
        const unsigned short* ap = x + (size_t)(tile * 16 + r16) * HD;
        f32x4 acc = {0.f, 0.f, 0.f, 0.f};
        #pragma unroll
        for (int kc = 0; kc < 4; ++kc) {
            short8 fa = *reinterpret_cast<const short8*>(ap + kc * 32 + g * 8);
            acc = __builtin_amdgcn_mfma_f32_16x16x32_bf16(fa, fb[kc], acc, 0, 0, 0);
        }
        #pragma unroll
        for (int r = 0; r < 4; ++r)
            z3[(size_t)(tile * 16 + g * 4 + r) * 16 + r16] = f2bf_rne(acc[r]);
    }
}

// ============ aggregate z3 (16-wide) + bias + sigmoid -> out(f32) ============
__global__ __launch_bounds__(256, 4) void k_agg16(const unsigned short* __restrict__ z3,
                                                  const int* __restrict__ rowptr,
                                                  const int* __restrict__ eidx,
                                                  const float* __restrict__ invd,
                                                  const float* __restrict__ bias,
                                                  float* __restrict__ out) {
    const unsigned* zp = reinterpret_cast<const unsigned*>(z3);
    int lane = threadIdx.x & 63, wid = threadIdx.x >> 6;
    int grp = lane >> 3, sub = lane & 7;
    float blo = bias[2 * sub], bhi = bias[2 * sub + 1];
    int step = gridDim.x * 32;
    for (int nb = blockIdx.x * 32 + wid * 8; nb < N_NODES; nb += step) {
        int node = nb + grp;
        bool valid = node < N_NODES;
        int rp0 = valid ? rowptr[node] : 0;
        int rp1 = valid ? rowptr[node + 1] : 0;
        float a0 = 0.f, a1 = 0.f;
        for (int base = rp0; base < rp1; base += 8) {
            int m = rp1 - base; if (m > 8) m = 8;
            int idx = (sub < m) ? eidx[base + sub] : 0;
            #pragma unroll
            for (int t = 0; t < 8; ++t) {
                if (t < m) {
                    int j = __shfl(idx, (grp << 3) + t);
                    unsigned v = zp[(size_t)j * 8 + sub];
                    a0 += bf16lo(v); a1 += bf16hi(v);
                }
            }
        }
        if (valid) {
            unsigned zv = zp[(size_t)node * 8 + sub];
            float s = invd[node];
            out[(size_t)node * 16 + sub * 2]     = sigmoidf_(bf16lo(zv) + s * a0 + blo);
            out[(size_t)node * 16 + sub * 2 + 1] = sigmoidf_(bf16hi(zv) + s * a1 + bhi);
        }
    }
}

extern "C" void kernel_launch(void* const* d_in, const int* in_sizes, int n_in,
                              void* d_out, int out_size, void* d_ws, size_t ws_size,
                              hipStream_t stream) {
    const float* feat0 = (const float*)d_in[0];
    const float* feat1 = (const float*)d_in[1];
    const int*   src   = (const int*)d_in[2];
    const int*   dst   = (const int*)d_in[3];
    const float* Wfc0  = (const float*)d_in[4];
    const float* bfc0  = (const float*)d_in[5];
    const float* Wfc1  = (const float*)d_in[6];
    const float* bfc1  = (const float*)d_in[7];
    const float* Wg0   = (const float*)d_in[8];
    const float* bg0   = (const float*)d_in[9];
    const float* Wg1   = (const float*)d_in[10];
    const float* bg1   = (const float*)d_in[11];
    const float* Wout  = (const float*)d_in[12];
    const float* bout  = (const float*)d_in[13];

    char* w = (char*)d_ws;
    auto alloc = [&](size_t bytes) {
        char* p = w;
        w += (bytes + 255) & ~(size_t)255;
        return p;
    };
    unsigned short* h      = (unsigned short*)alloc((size_t)N_NODES * HD * 2);   // 25.6 MB
    unsigned short* z      = (unsigned short*)alloc((size_t)N_NODES * HD * 2);   // 25.6 MB
    unsigned short* z3     = (unsigned short*)alloc((size_t)N_NODES * 16 * 2);   // 3.2 MB
    int*   rowptr = (int*)alloc((size_t)(N_NODES + 1) * 4);
    float* invd   = (float*)alloc((size_t)N_NODES * 4);
    int*   eidx   = (int*)alloc((size_t)NE * 4);                                 // 6.4 MB
    int*   cnt    = (int*)alloc((size_t)NB * NBLK * 4);                          // 1.96 MB
    int*   bcnt   = (int*)alloc((size_t)NB * 4);
    int*   boff   = (int*)alloc((size_t)(NB + 1) * 4);
    unsigned short* Wt_fc0 = (unsigned short*)alloc(512 * 128 * 2);
    unsigned short* Wt_fc1 = (unsigned short*)alloc(256 * 128 * 2);
    unsigned short* Wt_g0  = (unsigned short*)alloc(128 * 128 * 2);
    unsigned short* Wt_g1  = (unsigned short*)alloc(128 * 128 * 2);
    unsigned short* Wt_out = (unsigned short*)alloc(128 * 16 * 2);
    unsigned* ebuf = (unsigned*)z;   // aliases z: CSR build finishes before z is written

    // CSR build — radix partition, zero global atomics
    k_phist<<<NBLK, 256, 0, stream>>>(dst, cnt);
    k_colscan<<<NB, 64, 0, stream>>>(cnt, bcnt);
    k_bscan<<<1, 64, 0, stream>>>(bcnt, boff, rowptr);
    k_pplace<<<NBLK, 256, 0, stream>>>(src, dst, boff, cnt, ebuf);
    k_bplace<<<NB, 256, 0, stream>>>(ebuf, boff, rowptr, invd, eidx);

    prep_w_all<<<520, 256, 0, stream>>>(Wfc0, Wt_fc0, Wfc1, Wt_fc1,
                                        Wg0, Wt_g0, Wg1, Wt_g1, Wout, Wt_out);

    k_proj<512><<<N0_ROWS / 16, 256, 0, stream>>>(feat0, Wt_fc0, bfc0, h, N0_ROWS, 0);
    k_proj<256><<<N1_ROWS / 16, 256, 0, stream>>>(feat1, Wt_fc1, bfc1, h, N1_ROWS, N0_ROWS);

    // layer 1: z1 = h @ Wg0 ; h = sigmoid(z1 + mean_neigh(z1) + b)
    k_z_gemm<<<2084, 256, 0, stream>>>(h, Wt_g0, z);
    k_aggz<<<2048, 256, 0, stream>>>(z, rowptr, eidx, invd, bg0, h);
    // layer 2
    k_z_gemm<<<2084, 256, 0, stream>>>(h, Wt_g1, z);
    k_aggz<<<2048, 256, 0, stream>>>(z, rowptr, eidx, invd, bg1, h);
    // layer 3: z3 = h @ Wout (N x 16) ; out = sigmoid(z3 + mean_neigh(z3) + b)
    k_zout_gemm<<<1563, 256, 0, stream>>>(h, Wt_out, z3);
    k_agg16<<<2048, 256, 0, stream>>>(z3, rowptr, eidx, invd, bout, (float*)d_out);
}

// Round 5
// 304.028 us; speedup vs baseline: 1.3593x; 1.3593x over previous
//
#include <hip/hip_runtime.h>
#include <hip/hip_bf16.h>

#define N_NODES 100000
#define N0_ROWS 60000
#define N1_ROWS 40000
#define NE 1600000
#define HD 128
#define NB 782           // ceil(100000/128) buckets of 128 nodes
#define BSH 128          // nodes per bucket
#define EPB 2560         // edges per partition block
#define NBLK 625         // NE / EPB exactly

typedef __attribute__((ext_vector_type(8))) short short8;
typedef __attribute__((ext_vector_type(4))) float f32x4;

__device__ __forceinline__ float bf16lo(unsigned v) { return __uint_as_float(v << 16); }
__device__ __forceinline__ float bf16hi(unsigned v) { return __uint_as_float(v & 0xFFFF0000u); }

__device__ __forceinline__ unsigned short f2bf_rne(float f) {
    unsigned u = __float_as_uint(f);
    return (unsigned short)((u + 0x7FFFu + ((u >> 16) & 1u)) >> 16);
}
__device__ __forceinline__ unsigned pack2_rne(float lo, float hi) {
    unsigned a = __float_as_uint(lo); a = (a + 0x7FFFu + ((a >> 16) & 1u)) >> 16;
    unsigned b = __float_as_uint(hi); b = (b + 0x7FFFu + ((b >> 16) & 1u)) & 0xFFFF0000u;
    return (a & 0xFFFFu) | b;
}
__device__ __forceinline__ float sigmoidf_(float v) { return 1.0f / (1.0f + __expf(-v)); }

// ============ CSR build: radix-partition (no global atomics) ============
__global__ __launch_bounds__(256) void k_phist(const int* __restrict__ dst,
                                               int* __restrict__ cnt) {
    __shared__ int h[NB];
    int blk = blockIdx.x;
    for (int i = threadIdx.x; i < NB; i += 256) h[i] = 0;
    __syncthreads();
    int e0 = blk * EPB;
    for (int e = e0 + threadIdx.x; e < e0 + EPB; e += 256)
        atomicAdd(&h[dst[e] >> 7], 1);
    __syncthreads();
    for (int i = threadIdx.x; i < NB; i += 256)
        cnt[i * NBLK + blk] = h[i];
}

__global__ __launch_bounds__(64) void k_colscan(int* __restrict__ cnt,
                                                int* __restrict__ bcnt) {
    int b = blockIdx.x, lane = threadIdx.x & 63;
    int* col = cnt + (size_t)b * NBLK;
    int carry = 0;
    for (int base = 0; base < NBLK; base += 64) {
        int i = base + lane;
        int v = (i < NBLK) ? col[i] : 0;
        int s = v;
        #pragma unroll
        for (int off = 1; off < 64; off <<= 1) {
            int t = __shfl_up(s, off);
            if (lane >= off) s += t;
        }
        if (i < NBLK) col[i] = carry + s - v;
        carry += __shfl(s, 63);
    }
    if (lane == 0) bcnt[b] = carry;
}

__global__ void k_bscan(const int* __restrict__ bcnt, int* __restrict__ boff,
                        int* __restrict__ rowptr) {
    int lane = threadIdx.x & 63;
    const int CH = (NB + 63) / 64;   // 13
    int base = lane * CH;
    int t = 0;
    for (int c = 0; c < CH; ++c) {
        int i = base + c;
        t += (i < NB) ? bcnt[i] : 0;
    }
    int s = t;
    #pragma unroll
    for (int off = 1; off < 64; off <<= 1) {
        int u = __shfl_up(s, off);
        if (lane >= off) s += u;
    }
    int running = s - t;
    for (int c = 0; c < CH; ++c) {
        int i = base + c;
        if (i < NB) {
            boff[i] = running;
            running += bcnt[i];
        }
    }
    if (lane == 0) { boff[NB] = NE; rowptr[N_NODES] = NE; }
}

__global__ __launch_bounds__(256) void k_pplace(const int* __restrict__ src,
                                                const int* __restrict__ dst,
                                                const int* __restrict__ boff,
                                                const int* __restrict__ cnt,
                                                unsigned* __restrict__ ebuf) {
    __shared__ int h[NB];
    int blk = blockIdx.x;
    for (int i = threadIdx.x; i < NB; i += 256) h[i] = cnt[i * NBLK + blk];
    __syncthreads();
    int e0 = blk * EPB;
    for (int e = e0 + threadIdx.x; e < e0 + EPB; e += 256) {
        int d = dst[e];
        int b = d >> 7;
        int pos = atomicAdd(&h[b], 1);
        ebuf[boff[b] + pos] = ((unsigned)(d & 127) << 17) | (unsigned)src[e];
    }
}

__global__ __launch_bounds__(256) void k_bplace(const unsigned* __restrict__ ebuf,
                                                const int* __restrict__ boff,
                                                int* __restrict__ rowptr,
                                                float* __restrict__ invd,
                                                int* __restrict__ eidx) {
    __shared__ int cnt[BSH], off[BSH], lcnt[BSH];
    int b = blockIdx.x, tid = threadIdx.x;
    int e0 = boff[b], e1 = boff[b + 1];
    for (int i = tid; i < BSH; i += 256) { cnt[i] = 0; lcnt[i] = 0; }
    __syncthreads();
    for (int e = e0 + tid; e < e1; e += 256)
        atomicAdd(&cnt[ebuf[e] >> 17], 1);
    __syncthreads();
    if (tid < 64) {
        int lane = tid;
        int c0 = cnt[2 * lane], c1 = cnt[2 * lane + 1];
        int t = c0 + c1, s = t;
        #pragma unroll
        for (int o = 1; o < 64; o <<= 1) {
            int u = __shfl_up(s, o);
            if (lane >= o) s += u;
        }
        int excl = s - t;
        off[2 * lane] = excl;
        off[2 * lane + 1] = excl + c0;
    }
    __syncthreads();
    for (int i = tid; i < BSH; i += 256) {
        int node = b * BSH + i;
        if (node < N_NODES) {
            rowptr[node] = e0 + off[i];
            invd[node] = 1.0f / fmaxf((float)cnt[i], 1.0f);
        }
    }
    for (int e = e0 + tid; e < e1; e += 256) {
        unsigned ent = ebuf[e];
        int d = ent >> 17;
        int pos = e0 + off[d] + atomicAdd(&lcnt[d], 1);
        eidx[pos] = (int)(ent & 0x1FFFFu);
    }
}

// ============ weight prep: all 5 weights, one launch ============
__global__ void prep_w_all(const float* __restrict__ W0, unsigned short* __restrict__ T0,   // 512x128
                           const float* __restrict__ W1, unsigned short* __restrict__ T1,   // 256x128
                           const float* __restrict__ W2, unsigned short* __restrict__ T2,   // 128x128
                           const float* __restrict__ W3, unsigned short* __restrict__ T3,   // 128x128
                           const float* __restrict__ W4, unsigned short* __restrict__ T4) { // 128x16
    int gid = blockIdx.x * blockDim.x + threadIdx.x;
    int stride = gridDim.x * blockDim.x;
    const int S0 = 512 * 128, S1 = 256 * 128, S2 = 128 * 128, S3 = 128 * 128, S4 = 128 * 16;
    const int E1 = S0 + S1, E2 = E1 + S2, E3 = E2 + S3, E4 = E3 + S4;
    for (int i = gid; i < E4; i += stride) {
        if (i < S0) {
            int n = i / 512, k = i - n * 512;
            T0[i] = f2bf_rne(W0[k * 128 + n]);
        } else if (i < E1) {
            int j = i - S0; int n = j / 256, k = j - n * 256;
            T1[j] = f2bf_rne(W1[k * 128 + n]);
        } else if (i < E2) {
            int j = i - E1; int n = j / 128, k = j - n * 128;
            T2[j] = f2bf_rne(W2[k * 128 + n]);
        } else if (i < E3) {
            int j = i - E2; int n = j / 128, k = j - n * 128;
            T3[j] = f2bf_rne(W3[k * 128 + n]);
        } else {
            int j = i - E3; int n = j / 128, k = j - n * 128;
            T4[j] = f2bf_rne(W4[k * 16 + n]);
        }
    }
}

// ============ input projection: cooperative LDS-staged tile ============
// Block = 512 threads (8 waves). Tile = 16 rows x 128 cols. A staged once
// per block in LDS (f32 -> bf16); each wave owns 16 output columns with
// register-resident weight fragments (fb[KC] = K/32 short8 = K/8 VGPRs).
template <int K>
__global__ __launch_bounds__(512, 4) void k_proj(const float* __restrict__ feat,
                                                 const unsigned short* __restrict__ Wt,
                                                 const float* __restrict__ bias,
                                                 unsigned short* __restrict__ hout,
                                                 int ntiles, int row_off) {
    constexpr int KC = K / 32;
    __shared__ unsigned short A_lds[16][K + 8];   // +8 bf16 pad: stride 1040 B -> ~2-way banks

    const int tid = threadIdx.x;
    const int lane = tid & 63, w = tid >> 6;      // wave id 0..7
    const int g = lane >> 4, r16 = lane & 15;
    const int col = w * 16 + r16;

    short8 fb[KC];
    #pragma unroll
    for (int kc = 0; kc < KC; ++kc)
        fb[kc] = *reinterpret_cast<const short8*>(Wt + (size_t)col * K + kc * 32 + g * 8);
    const float bv = bias[col];

    const int srow = tid >> 5;                    // 0..15
    const int sseg = tid & 31;                    // 0..31

    for (int tile = blockIdx.x; tile < ntiles; tile += gridDim.x) {
        __syncthreads();   // protect LDS from previous iteration's readers
        const float4* rowp = reinterpret_cast<const float4*>(feat + (size_t)(tile * 16 + srow) * K);
        #pragma unroll
        for (int s = 0; s < K / 128; ++s) {
            float4 v = rowp[sseg + s * 32];
            unsigned lo = __builtin_amdgcn_perm(__float_as_uint(v.y), __float_as_uint(v.x), 0x07060302u);
            unsigned hi = __builtin_amdgcn_perm(__float_as_uint(v.w), __float_as_uint(v.z), 0x07060302u);
            *reinterpret_cast<uint2*>(&A_lds[srow][(sseg + s * 32) * 4]) = make_uint2(lo, hi);
        }
        __syncthreads();
        f32x4 acc = {0.f, 0.f, 0.f, 0.f};
        #pragma unroll
        for (int kc = 0; kc < KC; ++kc) {
            short8 fa = *reinterpret_cast<const short8*>(&A_lds[r16][kc * 32 + g * 8]);
            acc = __builtin_amdgcn_mfma_f32_16x16x32_bf16(fa, fb[kc], acc, 0, 0, 0);
        }
        #pragma unroll
        for (int r = 0; r < 4; ++r) {
            size_t orow = (size_t)(row_off + tile * 16 + g * 4 + r);
            hout[orow * HD + col] = f2bf_rne(acc[r] + bv);
        }
    }
}

// ============ pure GEMM: z = h @ W (128->128), bf16 out, no bias ============
__global__ __launch_bounds__(256, 4) void k_z_gemm(const unsigned short* __restrict__ x,
                                                   const unsigned short* __restrict__ Wt,
                                                   unsigned short* __restrict__ zout) {
    const int lane = threadIdx.x & 63, wid = threadIdx.x >> 6;
    const int g = lane >> 4, r16 = lane & 15;
    const int colbase = wid * 32;

    short8 fb[2][4];
    #pragma unroll
    for (int nt = 0; nt < 2; ++nt) {
        int n = colbase + nt * 16 + r16;
        #pragma unroll
        for (int kc = 0; kc < 4; ++kc)
            fb[nt][kc] = *reinterpret_cast<const short8*>(Wt + (size_t)n * HD + kc * 32 + g * 8);
    }

    const int ntiles = N_NODES / 16;  // 6250
    for (int tile = blockIdx.x; tile < ntiles; tile += gridDim.x) {
        const unsigned short* ap = x + (size_t)(tile * 16 + r16) * HD;
        f32x4 acc0 = {0.f, 0.f, 0.f, 0.f};
        f32x4 acc1 = {0.f, 0.f, 0.f, 0.f};
        #pragma unroll
        for (int kc = 0; kc < 4; ++kc) {
            short8 fa = *reinterpret_cast<const short8*>(ap + kc * 32 + g * 8);
            acc0 = __builtin_amdgcn_mfma_f32_16x16x32_bf16(fa, fb[0][kc], acc0, 0, 0, 0);
            acc1 = __builtin_amdgcn_mfma_f32_16x16x32_bf16(fa, fb[1][kc], acc1, 0, 0, 0);
        }
        #pragma unroll
        for (int r = 0; r < 4; ++r) {
            size_t orow = (size_t)(tile * 16 + g * 4 + r);
            zout[orow * HD + colbase + r16]      = f2bf_rne(acc0[r]);
            zout[orow * HD + colbase + 16 + r16] = f2bf_rne(acc1[r]);
        }
    }
}

// ============ aggregate z (128-wide) + bias + sigmoid -> h(bf16) ============
__global__ __launch_bounds__(256, 4) void k_aggz(const unsigned short* __restrict__ z,
                                                 const int* __restrict__ rowptr,
                                                 const int* __restrict__ eidx,
                                                 const float* __restrict__ invd,
                                                 const float* __restrict__ bias,
                                                 unsigned short* __restrict__ hout) {
    const unsigned* zp = reinterpret_cast<const unsigned*>(z);
    unsigned* hp = reinterpret_cast<unsigned*>(hout);
    int lane = threadIdx.x & 63, wid = threadIdx.x >> 6;
    float blo = bias[2 * lane], bhi = bias[2 * lane + 1];
    int nwaves = gridDim.x * 4;
    for (int node = blockIdx.x * 4 + wid; node < N_NODES; node += nwaves) {
        int rp0 = rowptr[node], rp1 = rowptr[node + 1];
        float a0 = 0.f, a1 = 0.f;
        for (int base = rp0; base < rp1; base += 64) {
            int m = rp1 - base; if (m > 64) m = 64;
            int idx = (lane < m) ? eidx[base + lane] : 0;
            int t = 0;
            for (; t + 4 <= m; t += 4) {
                int j0 = __shfl(idx, t), j1 = __shfl(idx, t + 1);
                int j2 = __shfl(idx, t + 2), j3 = __shfl(idx, t + 3);
                unsigned v0 = zp[(size_t)j0 * 64 + lane];
                unsigned v1 = zp[(size_t)j1 * 64 + lane];
                unsigned v2 = zp[(size_t)j2 * 64 + lane];
                unsigned v3 = zp[(size_t)j3 * 64 + lane];
                a0 += bf16lo(v0) + bf16lo(v1) + bf16lo(v2) + bf16lo(v3);
                a1 += bf16hi(v0) + bf16hi(v1) + bf16hi(v2) + bf16hi(v3);
            }
            for (; t < m; ++t) {
                int j = __shfl(idx, t);
                unsigned v = zp[(size_t)j * 64 + lane];
                a0 += bf16lo(v); a1 += bf16hi(v);
            }
        }
        unsigned zv = zp[(size_t)node * 64 + lane];
        float s = invd[node];
        hp[(size_t)node * 64 + lane] = pack2_rne(sigmoidf_(bf16lo(zv) + s * a0 + blo),
                                                 sigmoidf_(bf16hi(zv) + s * a1 + bhi));
    }
}

// ============ z3 = x @ Wout (128->16), bf16 out, no bias ============
__global__ __launch_bounds__(256, 4) void k_zout_gemm(const unsigned short* __restrict__ x,
                                                      const unsigned short* __restrict__ Wt,
                                                      unsigned short* __restrict__ z3) {
    const int lane = threadIdx.x & 63, wid = threadIdx.x >> 6;
    const int g = lane >> 4, r16 = lane & 15;

    short8 fb[4];
    #pragma unroll
    for (int kc = 0; kc < 4; ++kc)
        fb[kc] = *reinterpret_cast<const short8*>(Wt + (size_t)r16 * HD + kc * 32 + g * 8);

    const int ntiles = N_NODES / 16;  // 6250
    for (int tile = blockIdx.x * 4 + wid; tile < ntiles; tile += gridDim.x * 4) {
        const unsigned short* ap = x + (size_t)(tile * 16 + r16) * HD;
        f32x4 acc = {0.f, 0.f, 0.f, 0.f};
        #pragma unroll
        for (int kc = 0; kc < 4; ++kc) {
            short8 fa = *reinterpret_cast<const short8*>(ap + kc * 32 + g * 8);
            acc = __builtin_amdgcn_mfma_f32_16x16x32_bf16(fa, fb[kc], acc, 0, 0, 0);
        }
        #pragma unroll
        for (int r = 0; r < 4; ++r)
            z3[(size_t)(tile * 16 + g * 4 + r) * 16 + r16] = f2bf_rne(acc[r]);
    }
}

// ============ aggregate z3 (16-wide) + bias + sigmoid -> out(f32) ============
__global__ __launch_bounds__(256, 4) void k_agg16(const unsigned short* __restrict__ z3,
                                                  const int* __restrict__ rowptr,
                                                  const int* __restrict__ eidx,
                                                  const float* __restrict__ invd,
                                                  const float* __restrict__ bias,
                                                  float* __restrict__ out) {
    const unsigned* zp = reinterpret_cast<const unsigned*>(z3);
    int lane = threadIdx.x & 63, wid = threadIdx.x >> 6;
    int grp = lane >> 3, sub = lane & 7;
    float blo = bias[2 * sub], bhi = bias[2 * sub + 1];
    int step = gridDim.x * 32;
    for (int nb = blockIdx.x * 32 + wid * 8; nb < N_NODES; nb += step) {
        int node = nb + grp;
        bool valid = node < N_NODES;
        int rp0 = valid ? rowptr[node] : 0;
        int rp1 = valid ? rowptr[node + 1] : 0;
        float a0 = 0.f, a1 = 0.f;
        for (int base = rp0; base < rp1; base += 8) {
            int m = rp1 - base; if (m > 8) m = 8;
            int idx = (sub < m) ? eidx[base + sub] : 0;
            #pragma unroll
            for (int t = 0; t < 8; ++t) {
                if (t < m) {
                    int j = __shfl(idx, (grp << 3) + t);
                    unsigned v = zp[(size_t)j * 8 + sub];
                    a0 += bf16lo(v); a1 += bf16hi(v);
                }
            }
        }
        if (valid) {
            unsigned zv = zp[(size_t)node * 8 + sub];
            float s = invd[node];
            out[(size_t)node * 16 + sub * 2]     = sigmoidf_(bf16lo(zv) + s * a0 + blo);
            out[(size_t)node * 16 + sub * 2 + 1] = sigmoidf_(bf16hi(zv) + s * a1 + bhi);
        }
    }
}

extern "C" void kernel_launch(void* const* d_in, const int* in_sizes, int n_in,
                              void* d_out, int out_size, void* d_ws, size_t ws_size,
                              hipStream_t stream) {
    const float* feat0 = (const float*)d_in[0];
    const float* feat1 = (const float*)d_in[1];
    const int*   src   = (const int*)d_in[2];
    const int*   dst   = (const int*)d_in[3];
    const float* Wfc0  = (const float*)d_in[4];
    const float* bfc0  = (const float*)d_in[5];
    const float* Wfc1  = (const float*)d_in[6];
    const float* bfc1  = (const float*)d_in[7];
    const float* Wg0   = (const float*)d_in[8];
    const float* bg0   = (const float*)d_in[9];
    const float* Wg1   = (const float*)d_in[10];
    const float* bg1   = (const float*)d_in[11];
    const float* Wout  = (const float*)d_in[12];
    const float* bout  = (const float*)d_in[13];

    char* w = (char*)d_ws;
    auto alloc = [&](size_t bytes) {
        char* p = w;
        w += (bytes + 255) & ~(size_t)255;
        return p;
    };
    unsigned short* h      = (unsigned short*)alloc((size_t)N_NODES * HD * 2);   // 25.6 MB
    unsigned short* z      = (unsigned short*)alloc((size_t)N_NODES * HD * 2);   // 25.6 MB
    unsigned short* z3     = (unsigned short*)alloc((size_t)N_NODES * 16 * 2);   // 3.2 MB
    int*   rowptr = (int*)alloc((size_t)(N_NODES + 1) * 4);
    float* invd   = (float*)alloc((size_t)N_NODES * 4);
    int*   eidx   = (int*)alloc((size_t)NE * 4);                                 // 6.4 MB
    int*   cnt    = (int*)alloc((size_t)NB * NBLK * 4);                          // 1.96 MB
    int*   bcnt   = (int*)alloc((size_t)NB * 4);
    int*   boff   = (int*)alloc((size_t)(NB + 1) * 4);
    unsigned short* Wt_fc0 = (unsigned short*)alloc(512 * 128 * 2);
    unsigned short* Wt_fc1 = (unsigned short*)alloc(256 * 128 * 2);
    unsigned short* Wt_g0  = (unsigned short*)alloc(128 * 128 * 2);
    unsigned short* Wt_g1  = (unsigned short*)alloc(128 * 128 * 2);
    unsigned short* Wt_out = (unsigned short*)alloc(128 * 16 * 2);
    unsigned* ebuf = (unsigned*)z;   // aliases z: CSR build finishes before z is written

    // CSR build — radix partition, zero global atomics
    k_phist<<<NBLK, 256, 0, stream>>>(dst, cnt);
    k_colscan<<<NB, 64, 0, stream>>>(cnt, bcnt);
    k_bscan<<<1, 64, 0, stream>>>(bcnt, boff, rowptr);
    k_pplace<<<NBLK, 256, 0, stream>>>(src, dst, boff, cnt, ebuf);
    k_bplace<<<NB, 256, 0, stream>>>(ebuf, boff, rowptr, invd, eidx);

    prep_w_all<<<520, 256, 0, stream>>>(Wfc0, Wt_fc0, Wfc1, Wt_fc1,
                                        Wg0, Wt_g0, Wg1, Wt_g1, Wout, Wt_out);

    // cooperative LDS-staged projections: 512 blocks = exactly 2/CU
    k_proj<512><<<512, 512, 0, stream>>>(feat0, Wt_fc0, bfc0, h, N0_ROWS / 16, 0);
    k_proj<256><<<512, 512, 0, stream>>>(feat1, Wt_fc1, bfc1, h, N1_ROWS / 16, N0_ROWS);

    // layer 1: z1 = h @ Wg0 ; h = sigmoid(z1 + mean_neigh(z1) + b)
    k_z_gemm<<<2084, 256, 0, stream>>>(h, Wt_g0, z);
    k_aggz<<<2048, 256, 0, stream>>>(z, rowptr, eidx, invd, bg0, h);
    // layer 2
    k_z_gemm<<<2084, 256, 0, stream>>>(h, Wt_g1, z);
    k_aggz<<<2048, 256, 0, stream>>>(z, rowptr, eidx, invd, bg1, h);
    // layer 3: z3 = h @ Wout (N x 16) ; out = sigmoid(z3 + mean_neigh(z3) + b)
    k_zout_gemm<<<1563, 256, 0, stream>>>(h, Wt_out, z3);
    k_agg16<<<2048, 256, 0, stream>>>(z3, rowptr, eidx, invd, bout, (float*)d_out);
}